// Round 2
// baseline (350.788 us; speedup 1.0000x reference)
//
#include <hip/hip_runtime.h>

// Unfold: x (B=16, C=128, H=64, W=64) f32 -> y (B, C*9, H*W) f32
// y[bc, t, h*W+w] = x[bc, h+dh, w+dw] (zero-padded), t = (dh+1)*3 + (dw+1)
//
// Pure bandwidth problem: 33.5 MB in, 302 MB out. One thread per float4 of
// output (aligned, coalesced store); reads are contiguous-but-shifted rows of
// the 16 KB source plane (L1/L2-resident after first tap).

#define HW_BITS 12          // H*W = 4096
#define W_BITS  6           // W = 64
#define PLANE_W 64
#define PLANE_H 64

typedef float f32x4 __attribute__((ext_vector_type(4)));

__global__ __launch_bounds__(256) void unfold_kernel(
    const float* __restrict__ x, float* __restrict__ y, int total4) {
    int i = blockIdx.x * blockDim.x + threadIdx.x;
    if (i >= total4) return;

    int p     = i << 2;                  // first output pixel index (global)
    int pix   = p & ((1 << HW_BITS) - 1);
    int plane = p >> HW_BITS;            // (bc * 9 + t)
    int h = pix >> W_BITS;
    int w = pix & (PLANE_W - 1);         // multiple of 4

    int t  = plane % 9;
    int bc = plane / 9;
    int dh = t / 3 - 1;
    int dw = t % 3 - 1;

    int row = h + dh;
    f32x4 v = (f32x4)(0.f, 0.f, 0.f, 0.f);
    if (row >= 0 && row < PLANE_H) {
        const float* src = x + ((size_t)bc << HW_BITS) + ((size_t)row << W_BITS);
        int c0 = w + dw;                 // c0 in [-1, 61]
        // c0+1 in [0,62] and c0+2 in [1,63] are always in-bounds;
        // only the first (c0==-1) and last (c0+3==64) can fall off the row.
        v.x = (c0 >= 0)              ? src[c0]     : 0.f;
        v.y =                          src[c0 + 1];
        v.z =                          src[c0 + 2];
        v.w = (c0 + 3 < PLANE_W)     ? src[c0 + 3] : 0.f;
    }
    __builtin_nontemporal_store(v, ((f32x4*)y) + i);
}

extern "C" void kernel_launch(void* const* d_in, const int* in_sizes, int n_in,
                              void* d_out, int out_size, void* d_ws, size_t ws_size,
                              hipStream_t stream) {
    const float* x = (const float*)d_in[0];
    // d_in[1] is the fixed identity eye(9) kernel -- its effect is hard-coded.
    float* y = (float*)d_out;

    int total4 = out_size >> 2;          // out_size = 16*128*9*4096 = 75,497,472
    int block = 256;
    int grid = (total4 + block - 1) / block;
    unfold_kernel<<<grid, block, 0, stream>>>(x, y, total4);
}

// Round 3
// 326.785 us; speedup vs baseline: 1.0735x; 1.0735x over previous
//
#include <hip/hip_runtime.h>

// Unfold: x (B=16, C=128, H=64, W=64) f32 -> y (B, C*9, H*W) f32
// y[bc, t, h*W+w] = x[bc, h+dh, w+dw] (zero-padded), t = (dh+1)*3 + (dw+1)
//
// One block per (b,c) plane: read the 16 KB plane from HBM exactly once,
// stage into LDS with a zero halo, write 9 shifted copies coalesced.
// Traffic: 33.5 MB read + 302 MB written -> ~53 us floor at 6.3 TB/s.
//
// LDS layout: 66 rows x stride 67 floats (halo row/col 0 and 65; col 66 pad).
// Stride 67 => the wave's 4 row-groups (16 lanes each, stride-4 cols) hit
// disjoint bank residue classes mod 4 -> only 2-way aliasing (free).

#define LDS_STRIDE 67
#define LDS_ELEMS (66 * LDS_STRIDE)   // 4422 floats = 17.3 KB

typedef float f32x4 __attribute__((ext_vector_type(4)));

__global__ __launch_bounds__(256) void unfold_kernel(
    const float* __restrict__ x, float* __restrict__ y) {
    __shared__ float lds[LDS_ELEMS];
    const int j  = threadIdx.x;
    const int bc = blockIdx.x;

    // Zero everything (covers the halo), then overwrite the interior.
    for (int s = j; s < LDS_ELEMS; s += 256) lds[s] = 0.f;
    __syncthreads();

    const f32x4* plane = (const f32x4*)(x + ((size_t)bc << 12));
    #pragma unroll
    for (int q = 0; q < 4; ++q) {
        int f = q * 256 + j;           // float4 index within plane, 0..1023
        f32x4 v = plane[f];
        int h = f >> 4;                // 16 float4 per 64-wide row
        int w = (f & 15) << 2;
        float* dst = &lds[(h + 1) * LDS_STRIDE + (w + 1)];
        dst[0] = v.x; dst[1] = v.y; dst[2] = v.z; dst[3] = v.w;
    }
    __syncthreads();

    float* ybase = y + ((size_t)bc * 9 << 12);
    #pragma unroll
    for (int t = 0; t < 9; ++t) {
        const int dh = t / 3 - 1;
        const int dw = t % 3 - 1;
        f32x4* yt = (f32x4*)(ybase + ((size_t)t << 12));
        #pragma unroll
        for (int q = 0; q < 4; ++q) {
            int f = q * 256 + j;
            int h = f >> 4;
            int w = (f & 15) << 2;
            const float* s = &lds[(h + 1 + dh) * LDS_STRIDE + (w + 1 + dw)];
            f32x4 v;
            v.x = s[0]; v.y = s[1]; v.z = s[2]; v.w = s[3];
            yt[f] = v;                 // coalesced 16B store
        }
    }
}

extern "C" void kernel_launch(void* const* d_in, const int* in_sizes, int n_in,
                              void* d_out, int out_size, void* d_ws, size_t ws_size,
                              hipStream_t stream) {
    const float* x = (const float*)d_in[0];
    // d_in[1] is the fixed identity eye(9) kernel -- effect hard-coded.
    float* y = (float*)d_out;

    // B*C = 2048 planes -> 2048 blocks (8 per CU on 256 CUs), 256 threads.
    unfold_kernel<<<2048, 256, 0, stream>>>(x, y);
}

// Round 4
// 324.271 us; speedup vs baseline: 1.0818x; 1.0078x over previous
//
#include <hip/hip_runtime.h>

// Unfold: x (B=16, C=128, H=64, W=64) f32 -> y (B, C*9, H*W) f32
// y[bc, t, h*W+w] = x[bc, h+dh, w+dw] (zero-padded), t = (dh+1)*3 + (dw+1)
//
// One block per (b,c) plane: read the 16 KB plane from HBM exactly once,
// stage into LDS with a zero halo, write 9 shifted copies coalesced (nt).
// Traffic: 33.5 MB read + 302 MB written -> ~53 us floor at 6.3 TB/s.
//
// LDS: 66 rows x stride 67 (halo at row/col 0 and 65, col 66 pad). Stride 67
// puts the wave's four 16-lane row-groups on disjoint bank residues mod 4 ->
// only the free 2-way aliasing. Scalar b32 reads are fine: LDS pipe time
// (~11 us/CU-aggregate) hides under the ~48 us store drain.
//
// Ordering: issue the 4 global loads first, zero the halo while they are in
// flight, then write the interior -> a single barrier instead of two.

#define S 67
#define LDS_ELEMS (66 * S)

typedef float f32x4 __attribute__((ext_vector_type(4)));

__global__ __launch_bounds__(256) void unfold_kernel(
    const float* __restrict__ x, float* __restrict__ y) {
    __shared__ float lds[LDS_ELEMS];
    const int j  = threadIdx.x;
    const int bc = blockIdx.x;

    // 1) Issue the plane loads (4 x 16 B per thread, coalesced) immediately.
    const f32x4* plane = (const f32x4*)(x + ((size_t)bc << 12));
    f32x4 v0 = plane[j];
    f32x4 v1 = plane[256 + j];
    f32x4 v2 = plane[512 + j];
    f32x4 v3 = plane[768 + j];

    // 2) Zero only the halo (262 elements) while the loads are in flight.
    if (j < S) {
        lds[j] = 0.f;                 // top halo row
        lds[65 * S + j] = 0.f;        // bottom halo row
    }
    if (j < 64) {
        lds[(j + 1) * S] = 0.f;       // left halo col
        lds[(j + 1) * S + 65] = 0.f;  // right halo col
    }

    // 3) Interior writes (h = f>>4, w = (f&15)*4 for f = q*256 + j).
    #pragma unroll
    for (int q = 0; q < 4; ++q) {
        f32x4 v = (q == 0) ? v0 : (q == 1) ? v1 : (q == 2) ? v2 : v3;
        int f = q * 256 + j;
        int h = f >> 4;
        int w = (f & 15) << 2;
        float* dst = &lds[(h + 1) * S + (w + 1)];
        dst[0] = v.x; dst[1] = v.y; dst[2] = v.z; dst[3] = v.w;
    }
    __syncthreads();

    // 4) Emit the 9 shifted copies; nontemporal coalesced 16 B stores.
    float* ybase = y + ((size_t)bc * 9 << 12);
    #pragma unroll
    for (int t = 0; t < 9; ++t) {
        const int dh = t / 3 - 1;
        const int dw = t % 3 - 1;
        f32x4* yt = (f32x4*)(ybase + ((size_t)t << 12));
        #pragma unroll
        for (int q = 0; q < 4; ++q) {
            int f = q * 256 + j;
            int h = f >> 4;
            int w = (f & 15) << 2;
            const float* s = &lds[(h + 1 + dh) * S + (w + 1 + dw)];
            f32x4 v;
            v.x = s[0]; v.y = s[1]; v.z = s[2]; v.w = s[3];
            __builtin_nontemporal_store(v, yt + f);
        }
    }
}

extern "C" void kernel_launch(void* const* d_in, const int* in_sizes, int n_in,
                              void* d_out, int out_size, void* d_ws, size_t ws_size,
                              hipStream_t stream) {
    const float* x = (const float*)d_in[0];
    // d_in[1] is the fixed identity eye(9) kernel -- effect hard-coded.
    float* y = (float*)d_out;

    // B*C = 2048 planes -> 2048 blocks (8 per CU on 256 CUs = 32 waves/CU).
    unfold_kernel<<<2048, 256, 0, stream>>>(x, y);
}